// Round 1
// baseline (121.072 us; speedup 1.0000x reference)
//
#include <hip/hip_runtime.h>

#define F_SCALE 0.02581988897471611f   // 1/sqrt(1500)
#define F_LOG2E 1.4426950408889634f

constexpr int B_ = 32;
constexpr int L_ = 1500;

// A (float4) += s * e
#define ACC4(A, s, e) \
    A.x = fmaf(s, e.x, A.x); A.y = fmaf(s, e.y, A.y); \
    A.z = fmaf(s, e.z, A.z); A.w = fmaf(s, e.w, A.w)

// ---------------------------------------------------------------------------
// Whole pipeline fused: one block per batch, 512 threads, all intermediates in
// LDS. Phases (separated by __syncthreads):
//   0) stage signal window sw[1502]; fold M' = Wq^T Wk * SCALE, uu = Wk^T bq
//   A) moment pass: 3 chunks x 500 m-rows into umq (float4 pitch 7), each of
//      5 waves owns one 4-monomial group and accumulates 4xfloat4 in regs;
//      one-shot strip reduction -> Gacc4[20] (the 20x4 moment matrix G)
//   B) T(l) = S.xyz/S.w per l (1500), stored in umq (rows dead); then
//      conv1 with wv/bv folded into per-o A[8][3] -> h1 [32][376] in LDS
//   C) conv2 -> h2 [64][96] in LDS (aliases umq; TD dead). 4 o per thread
//      for register reuse of the h1 float4s (LDS ~= VALU ~= 12K cyc)
//   D) conv3 -> flat[176]; logit via 64-lane shfl reduce -> out[b][3]
// No workspace, no intermediate global traffic, single launch.
// ---------------------------------------------------------------------------
__global__ __launch_bounds__(512) void fused_all(
    const float* __restrict__ signal,
    const float* __restrict__ wq, const float* __restrict__ bq,
    const float* __restrict__ wk,
    const float* __restrict__ wv, const float* __restrict__ bv,
    const float* __restrict__ w1, const float* __restrict__ b1,
    const float* __restrict__ w2, const float* __restrict__ b2,
    const float* __restrict__ w3, const float* __restrict__ b3,
    const float* __restrict__ wl, const float* __restrict__ bl,
    float* __restrict__ out)
{
    __shared__ float  sw[1504];        // sig[-1..1502], zero-padded
    __shared__ float4 umq[3500];       // A: rows pitch 7 | B: TD[1500] | C: h2 [64][24]
    __shared__ float4 Gacc4[20];       // G moments (20 monomials x 4)
    __shared__ float4 h1q[32*94];      // h1 [32][376]; pre-conv1: red strip (6400 f)
    __shared__ float  flat[176];

    float4* const h2q = umq;           // alias, phase-disjoint
    float*  const red = (float*)h1q;   // alias, dead before conv1 writes h1

    const int tid = threadIdx.x;
    const int b   = blockIdx.x;
    const int wid = tid >> 6;          // wave id 0..7
    const int ln  = tid & 63;
    const float* sgb = signal + (size_t)b * L_;

    // ---- phase 0
    for (int i = tid; i < 1504; i += 512) {
        const int gi = i - 1;
        sw[i] = (gi >= 0 && gi < L_) ? sgb[gi] : 0.0f;
    }
    float Mm[9], uu[3];
    #pragma unroll
    for (int a = 0; a < 3; a++) {
        #pragma unroll
        for (int d = 0; d < 3; d++) {
            float acc = 0.0f;
            #pragma unroll
            for (int c = 0; c < 8; c++) acc += wq[c*3+a] * wk[c*3+d];
            Mm[a*3+d] = acc * F_SCALE;
        }
    }
    #pragma unroll
    for (int d = 0; d < 3; d++) {
        float acc = 0.0f;
        #pragma unroll
        for (int c = 0; c < 8; c++) acc += bq[c] * wk[c*3+d];
        uu[d] = acc * (F_SCALE * F_LOG2E);
    }
    __syncthreads();

    // ---- phase A: moments. wave w (<5) owns monomial group w (4 monomials),
    // accumulates acc[qq] = sum_m mono_qq(m) * (E*x0,E*x1,E*x2,E) in registers.
    float4 aq0 = make_float4(0,0,0,0), aq1 = aq0, aq2 = aq0, aq3 = aq0;

    for (int chk = 0; chk < 3; ++chk) {
        const int m0 = chk * 500;
        if (tid < 500) {
            const int j = tid;
            const float x0 = sw[m0+j], x1 = sw[m0+j+1], x2 = sw[m0+j+2];
            const float h0  = Mm[0]*x0 + Mm[1]*x1 + Mm[2]*x2;
            const float h1v = Mm[3]*x0 + Mm[4]*x1 + Mm[5]*x2;
            const float h2v = Mm[6]*x0 + Mm[7]*x1 + Mm[8]*x2;
            const float E   = __builtin_amdgcn_exp2f(uu[0]*x0 + uu[1]*x1 + uu[2]*x2);
            const float p00=h0*h0, p01=h0*h1v, p02=h0*h2v;
            const float p11=h1v*h1v, p12=h1v*h2v, p22=h2v*h2v;
            float4* row = &umq[j*7];
            row[0] = make_float4(E*x0, E*x1, E*x2, E);
            row[1] = make_float4(h0, h1v, h2v, p00);              // jm 1..4
            row[2] = make_float4(p01, p02, p11, p12);             // jm 5..8
            row[3] = make_float4(p22, h0*p00, h1v*p00, h2v*p00);  // jm 9..12
            row[4] = make_float4(h0*p11, h0*p12, h0*p22, h1v*p11);// jm 13..16
            row[5] = make_float4(h2v*p11, h1v*p22, h2v*p22, 1.0f);// jm 17,18,19,0
        }
        __syncthreads();
        if (wid < 5) {
            #pragma unroll
            for (int ii = 0; ii < 8; ++ii) {
                const int j = ln + 64*ii;
                if (j < 500) {
                    const float4 ex = umq[j*7];
                    const float4 mq = umq[j*7 + 1 + wid];
                    ACC4(aq0, mq.x, ex); ACC4(aq1, mq.y, ex);
                    ACC4(aq2, mq.z, ex); ACC4(aq3, mq.w, ex);
                }
            }
        }
        __syncthreads();
    }

    // one-shot 64-lane reduction via padded LDS strip (pitch 20 floats)
    if (wid < 5) {
        float4* rp = (float4*)&red[(wid*64 + ln)*20];
        rp[0] = aq0; rp[1] = aq1; rp[2] = aq2; rp[3] = aq3;
    }
    __syncthreads();
    if (tid < 80) {
        const int jm = tid >> 2, cc = tid & 3;
        int grp, qq;
        if (jm == 0)      { grp = 4; qq = 3; }
        else if (jm < 17) { grp = (jm-1) >> 2; qq = (jm-1) & 3; }
        else              { grp = 4; qq = jm - 17; }
        const float* rb = red + (size_t)grp*64*20 + qq*4 + cc;
        float val = 0.0f;
        #pragma unroll 8
        for (int l = 0; l < 64; ++l) val += rb[l*20];
        ((float*)Gacc4)[tid] = val;
    }
    __syncthreads();

    // ---- phase B: T(l) for all 1500 l (rows dead; umq becomes TD)
    for (int l = tid; l < 1500; l += 512) {
        const float y0 = sw[l], y1 = sw[l+1], y2 = sw[l+2];
        const float t00=y0*y0, t01=y0*y1, t02=y0*y2, t11=y1*y1, t12=y1*y2, t22=y2*y2;
        const float c6 = 1.0f/6.0f;
        float ym[20];
        ym[0]=1.0f; ym[1]=y0; ym[2]=y1; ym[3]=y2;
        ym[4]=0.5f*t00; ym[5]=t01; ym[6]=t02; ym[7]=0.5f*t11; ym[8]=t12; ym[9]=0.5f*t22;
        ym[10]=c6*(y0*t00);  ym[11]=0.5f*(y1*t00); ym[12]=0.5f*(y2*t00);
        ym[13]=0.5f*(y0*t11); ym[14]=y0*t12;       ym[15]=0.5f*(y0*t22);
        ym[16]=c6*(y1*t11);  ym[17]=0.5f*(y2*t11); ym[18]=0.5f*(y1*t22);
        ym[19]=c6*(y2*t22);
        float4 S = make_float4(0,0,0,0);
        #pragma unroll
        for (int jj = 0; jj < 20; ++jj) {
            const float4 G = Gacc4[jj];        // uniform b128 broadcast
            ACC4(S, ym[jj], G);
        }
        const float rd = 1.0f / S.w;
        umq[l] = make_float4(S.x*rd, S.y*rd, S.z*rd, 0.0f);
    }

    // conv1: fold wv/bv into per-o A[8][3], b1p (register-only, overlaps TD tail)
    {
        const int o = tid & 31, g = tid >> 5;
        float A[8][3];
        float b1p = b1[o];
        #pragma unroll
        for (int k = 0; k < 8; ++k) { A[k][0]=0.f; A[k][1]=0.f; A[k][2]=0.f; }
        #pragma unroll
        for (int i = 0; i < 8; ++i) {
            const float v0 = wv[i*3+0], v1 = wv[i*3+1], v2 = wv[i*3+2];
            const float bvi = bv[i];
            #pragma unroll
            for (int k = 0; k < 8; ++k) {
                const float w = w1[o*64 + i*8 + k];
                A[k][0] = fmaf(w, v0, A[k][0]);
                A[k][1] = fmaf(w, v1, A[k][1]);
                A[k][2] = fmaf(w, v2, A[k][2]);
                b1p     = fmaf(w, bvi, b1p);
            }
        }
        __syncthreads();                      // TD complete
        const float4* TD = umq;
        float* h1f = (float*)h1q;
        for (int t = g; t < 374; t += 16) {
            float acc = b1p;
            const int li = 4*t;
            #pragma unroll
            for (int k = 0; k < 8; ++k) {
                const float4 T = TD[li + k];
                acc += A[k][0]*T.x + A[k][1]*T.y + A[k][2]*T.z;
            }
            h1f[o*376 + t] = acc;
        }
    }
    __syncthreads();

    // ---- phase C: conv2. thread = (o-quad og, t-slot ts); 4 o x 3 t per thread
    {
        const int og = tid >> 5;              // 0..15
        const int ts = tid & 31;
        const int ob = 4*og;
        float acc2[3][4];
        #pragma unroll
        for (int j = 0; j < 3; ++j) {
            #pragma unroll
            for (int q = 0; q < 4; ++q) acc2[j][q] = b2[ob+q];
        }
        const float4* w2q4 = (const float4*)w2;
        #pragma unroll 2
        for (int i = 0; i < 32; ++i) {
            float4 wA[4], wB[4];
            #pragma unroll
            for (int q = 0; q < 4; ++q) {
                wA[q] = w2q4[(ob+q)*64 + 2*i];
                wB[q] = w2q4[(ob+q)*64 + 2*i + 1];
            }
            #pragma unroll
            for (int j = 0; j < 3; ++j) {
                const int t = ts + 32*j;
                if (t < 92) {
                    const float4 a0 = h1q[i*94 + t];
                    const float4 a1 = h1q[i*94 + t + 1];
                    #pragma unroll
                    for (int q = 0; q < 4; ++q) {
                        acc2[j][q] += a0.x*wA[q].x + a0.y*wA[q].y + a0.z*wA[q].z + a0.w*wA[q].w
                                    + a1.x*wB[q].x + a1.y*wB[q].y + a1.z*wB[q].z + a1.w*wB[q].w;
                    }
                }
            }
        }
        float* h2f = (float*)h2q;             // = umq region, TD dead
        #pragma unroll
        for (int j = 0; j < 3; ++j) {
            const int t = ts + 32*j;
            if (t < 92) {
                #pragma unroll
                for (int q = 0; q < 4; ++q) h2f[(ob+q)*96 + t] = acc2[j][q];
            }
        }
    }
    __syncthreads();

    // ---- phase D: conv3 -> flat, then logit
    if (tid < 176) {
        const int c3 = tid / 22, t = tid - c3*22;
        float acc = b3[c3];
        #pragma unroll 8
        for (int i = 0; i < 64; ++i) {
            const float4 a0 = h2q[i*24 + t];
            const float4 a1 = h2q[i*24 + t + 1];
            const float* w = w3 + (c3*64 + i)*8;
            acc += a0.x*w[0] + a0.y*w[1] + a0.z*w[2] + a0.w*w[3]
                 + a1.x*w[4] + a1.y*w[5] + a1.z*w[6] + a1.w*w[7];
        }
        flat[tid] = acc;
    }
    __syncthreads();
    if (tid < 192) {                          // 3 full waves, r = wid
        float acc = 0.0f;
        for (int n = ln; n < 176; n += 64) acc += flat[n] * wl[wid*176 + n];
        #pragma unroll
        for (int off = 32; off; off >>= 1) acc += __shfl_xor(acc, off, 64);
        if (ln == 0) out[b*3 + wid] = acc + bl[wid];
    }
}

extern "C" void kernel_launch(void* const* d_in, const int* in_sizes, int n_in,
                              void* d_out, int out_size, void* d_ws, size_t ws_size,
                              hipStream_t stream) {
    const float* signal = (const float*)d_in[0];
    const float* wq = (const float*)d_in[1];  const float* bq = (const float*)d_in[2];
    const float* wk = (const float*)d_in[3];  /* bk cancels in softmax */
    const float* wvp = (const float*)d_in[5]; const float* bv = (const float*)d_in[6];
    const float* w1 = (const float*)d_in[7];  const float* b1 = (const float*)d_in[8];
    const float* w2 = (const float*)d_in[9];  const float* b2 = (const float*)d_in[10];
    const float* w3 = (const float*)d_in[11]; const float* b3 = (const float*)d_in[12];
    const float* wl = (const float*)d_in[13]; const float* bl = (const float*)d_in[14];
    float* out = (float*)d_out;
    (void)d_ws; (void)ws_size;                // no workspace: no intermediate global traffic

    hipLaunchKernelGGL(fused_all, dim3(B_), dim3(512), 0, stream,
                       signal, wq, bq, wk, wvp, bv, w1, b1, w2, b2, w3, b3, wl, bl, out);
}